// Round 1
// baseline (540.659 us; speedup 1.0000x reference)
//
#include <hip/hip_runtime.h>
#include <hip/hip_bf16.h>
#include <stdint.h>

typedef __bf16 bf16;
typedef __bf16 bf16x8 __attribute__((ext_vector_type(8)));
typedef __bf16 bf16x4 __attribute__((ext_vector_type(4)));
typedef float  f32x4  __attribute__((ext_vector_type(4)));

#define AS_GLOBAL __attribute__((address_space(1)))
#define AS_LDS    __attribute__((address_space(3)))

__device__ __forceinline__ void gload_lds16(const bf16* g, bf16* l) {
    __builtin_amdgcn_global_load_lds((const AS_GLOBAL uint32_t*)g,
                                     (AS_LDS uint32_t*)l, 16, 0, 0);
}

// ---------------- convert fp32 -> bf16, 4 elems/thread ----------------
__global__ __launch_bounds__(256) void cvt_f32_to_bf16(const float* __restrict__ in,
                                                       bf16* __restrict__ out, int n4) {
    int i = blockIdx.x * 256 + threadIdx.x;
    if (i >= n4) return;
    const float4* p = (const float4*)in;
    float4 v = p[i];
    bf16x4 o;
    o[0] = (bf16)v.x; o[1] = (bf16)v.y; o[2] = (bf16)v.z; o[3] = (bf16)v.w;
    *(bf16x4*)(out + (size_t)i * 4) = o;
}

// ---------------- GEMM: C[M,N] = A[M,K] * B[N,K]^T  (bf16 in, CT out) ----------------
// 128x128 tile, BK=32, 256 threads (4 waves, 2x2), 16x16x32 bf16 MFMA (m97 structure).
template<typename CT>
__global__ __launch_bounds__(256) void gemm_bt(const bf16* __restrict__ A,
                                               const bf16* __restrict__ B,
                                               CT* __restrict__ C,
                                               int M, int N, int K, float scale) {
    __shared__ bf16 As[128 * 32];   // 8 KB
    __shared__ bf16 Bs[128 * 32];   // 8 KB

    const int tid  = threadIdx.x;
    const int lane = tid & 63;
    const int wave = tid >> 6;
    const int wr = wave >> 1, wc = wave & 1;

    // bijective XCD-aware swizzle (all launches have gridDim.x % 8 == 0)
    const int nbn = N >> 7;
    const int nwg = gridDim.x;
    const int cpx = nwg >> 3;
    const int swz = (blockIdx.x & 7) * cpx + (blockIdx.x >> 3);
    const int bm = swz / nbn, bn = swz % nbn;

    // staging map: chunk = tid + c*256 ; row = chunk/4 ; kcol = (chunk%4)*8
    const int r0  = tid >> 2;
    const int kc0 = (tid & 3) << 3;
    const bf16* Abase = A + (size_t)(bm * 128 + r0) * K + kc0;
    const bf16* Bbase = B + (size_t)(bn * 128 + r0) * K + kc0;
    bf16* AsDst = &As[tid * 8];
    bf16* BsDst = &Bs[tid * 8];

    const int frow = lane & 15;          // fragment M/N index
    const int fk   = (lane >> 4) << 3;   // fragment K offset: 0,8,16,24

    f32x4 acc[4][4] = {};

    for (int k0 = 0; k0 < K; k0 += 32) {
        gload_lds16(Abase + k0,                   AsDst);
        gload_lds16(Abase + k0 + (size_t)64 * K,  AsDst + 256 * 8);
        gload_lds16(Bbase + k0,                   BsDst);
        gload_lds16(Bbase + k0 + (size_t)64 * K,  BsDst + 256 * 8);
        asm volatile("s_waitcnt vmcnt(0)" ::: "memory");
        __syncthreads();

        bf16x8 af[4], bfr[4];
        #pragma unroll
        for (int m = 0; m < 4; ++m)
            af[m] = *(const bf16x8*)&As[(wr * 64 + m * 16 + frow) * 32 + fk];
        #pragma unroll
        for (int n = 0; n < 4; ++n)
            bfr[n] = *(const bf16x8*)&Bs[(wc * 64 + n * 16 + frow) * 32 + fk];

        #pragma unroll
        for (int m = 0; m < 4; ++m)
            #pragma unroll
            for (int n = 0; n < 4; ++n)
                acc[m][n] = __builtin_amdgcn_mfma_f32_16x16x32_bf16(af[m], bfr[n], acc[m][n], 0, 0, 0);

        __syncthreads();
    }

    // epilogue: C/D layout col = lane&15, row = (lane>>4)*4 + i   (m89/m91 verified)
    const int crow0 = bm * 128 + wr * 64 + ((lane >> 4) << 2);
    const int ccol0 = bn * 128 + wc * 64 + (lane & 15);
    #pragma unroll
    for (int m = 0; m < 4; ++m)
        #pragma unroll
        for (int n = 0; n < 4; ++n)
            #pragma unroll
            for (int i = 0; i < 4; ++i)
                C[(size_t)(crow0 + m * 16 + i) * N + (ccol0 + n * 16)] =
                    (CT)(acc[m][n][i] * scale);
}

// ---------------- row softmax in place over bf16 [rows x 8192] ----------------
__global__ __launch_bounds__(256) void softmax_row(bf16* __restrict__ Z, int cols) {
    __shared__ float buf[8192];   // 32 KB
    __shared__ float red[4];
    const int tid = threadIdx.x;
    bf16* zrow = Z + (size_t)blockIdx.x * cols;

    float lmax = -3.4e38f;
    #pragma unroll
    for (int it = 0; it < 4; ++it) {
        int idx = it * 2048 + tid * 8;
        bf16x8 v = *(const bf16x8*)(zrow + idx);
        #pragma unroll
        for (int j = 0; j < 8; ++j) {
            float f = (float)v[j];
            buf[idx + j] = f;
            lmax = fmaxf(lmax, f);
        }
    }
    #pragma unroll
    for (int o = 32; o; o >>= 1) lmax = fmaxf(lmax, __shfl_xor(lmax, o));
    if ((tid & 63) == 0) red[tid >> 6] = lmax;
    __syncthreads();
    const float gmax = fmaxf(fmaxf(red[0], red[1]), fmaxf(red[2], red[3]));
    __syncthreads();

    float lsum = 0.f;
    #pragma unroll
    for (int it = 0; it < 4; ++it) {
        int idx = it * 2048 + tid * 8;
        #pragma unroll
        for (int j = 0; j < 8; ++j) {
            float e = __expf(buf[idx + j] - gmax);
            buf[idx + j] = e;
            lsum += e;
        }
    }
    #pragma unroll
    for (int o = 32; o; o >>= 1) lsum += __shfl_xor(lsum, o);
    if ((tid & 63) == 0) red[tid >> 6] = lsum;
    __syncthreads();
    const float inv = 1.0f / (red[0] + red[1] + red[2] + red[3]);

    #pragma unroll
    for (int it = 0; it < 4; ++it) {
        int idx = it * 2048 + tid * 8;
        bf16x8 v;
        #pragma unroll
        for (int j = 0; j < 8; ++j) v[j] = (bf16)(buf[idx + j] * inv);
        *(bf16x8*)(zrow + idx) = v;
    }
}

// ---------------- bf16 transpose: VT[c][r] = V[r][c] ----------------
__global__ __launch_bounds__(256) void transpose_bf16(const ushort* __restrict__ V,
                                                      ushort* __restrict__ VT,
                                                      int R, int Ccols) {
    __shared__ ushort tile[32][33];
    const int tx = threadIdx.x, ty = threadIdx.y;
    const int r0 = blockIdx.y * 32, c0 = blockIdx.x * 32;
    #pragma unroll
    for (int i = 0; i < 32; i += 8)
        tile[ty + i][tx] = V[(size_t)(r0 + ty + i) * Ccols + c0 + tx];
    __syncthreads();
    #pragma unroll
    for (int i = 0; i < 32; i += 8)
        VT[(size_t)(c0 + ty + i) * R + r0 + tx] = tile[tx][ty + i];
}

extern "C" void kernel_launch(void* const* d_in, const int* in_sizes, int n_in,
                              void* d_out, int out_size, void* d_ws, size_t ws_size,
                              hipStream_t stream) {
    const float* h  = (const float*)d_in[0];
    const float* wq = (const float*)d_in[1];
    const float* wk = (const float*)d_in[2];
    const float* wv = (const float*)d_in[3];
    float* out = (float*)d_out;

    char* ws = (char*)d_ws;
    bf16* h_bf  = (bf16*)(ws);                          // 16 MB  [8192 x 1024]
    bf16* wq_bf = (bf16*)(ws + (16ull << 20));          //  2 MB
    bf16* wk_bf = (bf16*)(ws + (18ull << 20));          //  2 MB
    bf16* wv_bf = (bf16*)(ws + (20ull << 20));          //  2 MB
    bf16* Q     = (bf16*)(ws + (22ull << 20));          // 16 MB
    bf16* Kb    = (bf16*)(ws + (38ull << 20));          // 16 MB
    bf16* V     = (bf16*)(ws + (54ull << 20));          // 16 MB
    bf16* VT    = (bf16*)(ws + (70ull << 20));          // 16 MB  [1024 x 8192]
    bf16* Z     = (bf16*)(ws + (86ull << 20));          // 128 MB [8192 x 8192]

    // 1) convert inputs to bf16
    cvt_f32_to_bf16<<<8192, 256, 0, stream>>>(h,  h_bf,  (8192 * 1024) / 4);
    cvt_f32_to_bf16<<<1024, 256, 0, stream>>>(wq, wq_bf, (1024 * 1024) / 4);
    cvt_f32_to_bf16<<<1024, 256, 0, stream>>>(wk, wk_bf, (1024 * 1024) / 4);
    cvt_f32_to_bf16<<<1024, 256, 0, stream>>>(wv, wv_bf, (1024 * 1024) / 4);

    // 2) Q = h @ wq^T (scale folded), K = h @ wk^T, V = h @ wv^T
    const float qscale = 1.0f / 32.0f;   // 1/sqrt(1024)
    gemm_bt<bf16><<<512, 256, 0, stream>>>(h_bf, wq_bf, Q,  8192, 1024, 1024, qscale);
    gemm_bt<bf16><<<512, 256, 0, stream>>>(h_bf, wk_bf, Kb, 8192, 1024, 1024, 1.0f);
    gemm_bt<bf16><<<512, 256, 0, stream>>>(h_bf, wv_bf, V,  8192, 1024, 1024, 1.0f);

    // 3) VT = V^T
    transpose_bf16<<<dim3(1024 / 32, 8192 / 32), dim3(32, 8), 0, stream>>>(
        (const ushort*)V, (ushort*)VT, 8192, 1024);

    // 4) Z = Q @ K^T  (scaled logits, bf16)
    gemm_bt<bf16><<<4096, 256, 0, stream>>>(Q, Kb, Z, 8192, 8192, 1024, 1.0f);

    // 5) row softmax in place
    softmax_row<<<8192, 256, 0, stream>>>(Z, 8192);

    // 6) out = beta @ V  ==  beta[8192,8192] @ VT[1024,8192]^T
    gemm_bt<float><<<512, 256, 0, stream>>>(Z, VT, out, 8192, 1024, 8192, 1.0f);
}

// Round 2
// 414.007 us; speedup vs baseline: 1.3059x; 1.3059x over previous
//
#include <hip/hip_runtime.h>
#include <hip/hip_bf16.h>
#include <stdint.h>

typedef __bf16 bf16;
typedef __bf16 bf16x8 __attribute__((ext_vector_type(8)));
typedef __bf16 bf16x4 __attribute__((ext_vector_type(4)));
typedef float  f32x4  __attribute__((ext_vector_type(4)));

#define AS_GLOBAL __attribute__((address_space(1)))
#define AS_LDS    __attribute__((address_space(3)))

__device__ __forceinline__ void gload_lds16(const bf16* g, bf16* l) {
    __builtin_amdgcn_global_load_lds((const AS_GLOBAL uint32_t*)g,
                                     (AS_LDS uint32_t*)l, 16, 0, 0);
}
__device__ __forceinline__ void cfence() { asm volatile("" ::: "memory"); }

// ---------------- convert fp32 -> bf16, 4 elems/thread ----------------
__global__ __launch_bounds__(256) void cvt_f32_to_bf16(const float* __restrict__ in,
                                                       bf16* __restrict__ out, int n4) {
    int i = blockIdx.x * 256 + threadIdx.x;
    if (i >= n4) return;
    const float4* p = (const float4*)in;
    float4 v = p[i];
    bf16x4 o;
    o[0] = (bf16)v.x; o[1] = (bf16)v.y; o[2] = (bf16)v.z; o[3] = (bf16)v.w;
    *(bf16x4*)(out + (size_t)i * 4) = o;
}

// ============ 8-phase 256-row-tile GEMM: C[M,N] = A[M,K] * B[N,K]^T ============
// BM=256, BK=64, 512 threads = 8 waves (2M x 4N). Wave tile 128 x (BN/4).
// LDS: A dbuf 2x32KB + B dbuf 2x(BN*128B). XOR-swizzle: 16B-slot ^= (row&7),
// applied via inverse-swizzled GLOBAL source (linear global_load_lds dest) and
// swizzled ds_read address (rule 21: both-sides-or-neither).
// Stage schedule per K-tile t: p0:B0(t+1) p1:B1(t+1) p2:A0(t+2) p3:A1(t+2);
// end-of-tile s_waitcnt vmcnt(4) -> tile t+1 fully landed, 2 halves in flight.
template<typename CT, int BN>
__global__ __launch_bounds__(512, 2) void gemm8p(const bf16* __restrict__ A,
                                                 const bf16* __restrict__ B,
                                                 CT* __restrict__ C,
                                                 int M, int N, int K, float scale) {
    constexpr int NBH  = BN / 128;        // B halves per K-tile (1 or 2)
    constexpr int BBUF = NBH * 16384;     // B bytes per K-tile buffer
    constexpr int WN   = BN / 4;          // wave N span (64 or 32)
    constexpr int NR   = WN / 16;         // n-reps (4 or 2)
    constexpr int NH   = NR / 2;          // n-reps per phase-half (2 or 1)
    __shared__ char smem[65536 + 2 * BBUF];

    const int tid  = threadIdx.x;
    const int lane = tid & 63;
    const int wr   = (tid >> 6) >> 2;     // 0..1
    const int wc   = (tid >> 6) & 3;      // 0..3
    const int frow = lane & 15;
    const int fg   = lane >> 4;           // 0..3
    const int xorv = (frow & 7) << 4;

    const int nbn = N / BN;
    const int cpx = gridDim.x >> 3;
    const int swz = ((int)blockIdx.x & 7) * cpx + ((int)blockIdx.x >> 3);
    const int bm = swz / nbn, bn = swz % nbn;
    const int NT = K >> 6;

    // staging: per thread 2 chunks per half; physical slot s in [0,1024):
    // prow = s>>3, pslot = s&7, logical col16 = pslot ^ (prow&7)
    const int prow0 = tid >> 3,           c0 = ((tid & 7) ^ (prow0 & 7)) << 3;
    const int prow1 = (tid + 512) >> 3,   c1 = ((tid & 7) ^ (prow1 & 7)) << 3;
    const bf16* Asrc0 = A + (size_t)(bm * 256 + prow0) * K + c0;
    const bf16* Asrc1 = A + (size_t)(bm * 256 + prow1) * K + c1;
    const bf16* Bsrc0 = B + (size_t)(bn * BN  + prow0) * K + c0;
    const bf16* Bsrc1 = B + (size_t)(bn * BN  + prow1) * K + c1;

    auto stA = [&](int t, int h) {
        char* d = smem + ((t & 1) << 15) + (h << 14) + (tid << 4);
        gload_lds16(Asrc0 + (size_t)(h * 128) * K + t * 64, (bf16*)d);
        gload_lds16(Asrc1 + (size_t)(h * 128) * K + t * 64, (bf16*)(d + 8192));
    };
    auto stB = [&](int t, int h) {
        char* d = smem + 65536 + (t & 1) * BBUF + (h << 14) + (tid << 4);
        gload_lds16(Bsrc0 + (size_t)(h * 128) * K + t * 64, (bf16*)d);
        gload_lds16(Bsrc1 + (size_t)(h * 128) * K + t * 64, (bf16*)(d + 8192));
    };
    auto rdA = [&](int t, int m, int kk) -> bf16x8 {
        return *(const bf16x8*)(smem + ((t & 1) << 15) + (wr << 14)
                + (m * 16 + frow) * 128 + ((kk * 64 + (fg << 4)) ^ xorv));
    };
    auto rdB = [&](int t, int n, int kk) -> bf16x8 {
        int br = wc * WN + n * 16 + frow;
        return *(const bf16x8*)(smem + 65536 + (t & 1) * BBUF + ((br >> 7) << 14)
                + (br & 127) * 128 + ((kk * 64 + (fg << 4)) ^ xorv));
    };

    f32x4 acc[8][NR] = {};
    bf16x8 a0[4][2], a1[4][2], bl[NH][2], bh[NH][2];

    // prologue: tile0 all halves + tile1 A-halves; vmcnt(4) => tile0 landed
    stA(0, 0); stA(0, 1);
    stB(0, 0); if (NBH == 2) stB(0, 1);
    stA(1, 0); stA(1, 1);
    asm volatile("s_waitcnt vmcnt(4)" ::: "memory");
    __builtin_amdgcn_s_barrier();

    for (int t = 0; t < NT; ++t) {
        const int t1 = t + 1, t2 = t + 2;
        // ---- phase 0: read A-lo + B-lo ; stage B0(t+1) ; MFMA m0..3 x n-lo
        #pragma unroll
        for (int m = 0; m < 4; ++m) { a0[m][0] = rdA(t, m, 0); a0[m][1] = rdA(t, m, 1); }
        #pragma unroll
        for (int n = 0; n < NH; ++n) { bl[n][0] = rdB(t, n, 0); bl[n][1] = rdB(t, n, 1); }
        if (t1 < NT) stB(t1, 0);
        cfence(); __builtin_amdgcn_s_barrier();
        __builtin_amdgcn_s_setprio(1);
        #pragma unroll
        for (int m = 0; m < 4; ++m)
            #pragma unroll
            for (int n = 0; n < NH; ++n)
                #pragma unroll
                for (int kk = 0; kk < 2; ++kk)
                    acc[m][n] = __builtin_amdgcn_mfma_f32_16x16x32_bf16(a0[m][kk], bl[n][kk], acc[m][n], 0, 0, 0);
        __builtin_amdgcn_s_setprio(0);
        cfence(); __builtin_amdgcn_s_barrier();
        // ---- phase 1: read A-hi ; stage B1(t+1) ; MFMA m4..7 x n-lo
        #pragma unroll
        for (int m = 0; m < 4; ++m) { a1[m][0] = rdA(t, m + 4, 0); a1[m][1] = rdA(t, m + 4, 1); }
        if (NBH == 2 && t1 < NT) stB(t1, 1);
        cfence(); __builtin_amdgcn_s_barrier();
        __builtin_amdgcn_s_setprio(1);
        #pragma unroll
        for (int m = 0; m < 4; ++m)
            #pragma unroll
            for (int n = 0; n < NH; ++n)
                #pragma unroll
                for (int kk = 0; kk < 2; ++kk)
                    acc[m + 4][n] = __builtin_amdgcn_mfma_f32_16x16x32_bf16(a1[m][kk], bl[n][kk], acc[m + 4][n], 0, 0, 0);
        __builtin_amdgcn_s_setprio(0);
        cfence(); __builtin_amdgcn_s_barrier();
        // ---- phase 2: read B-hi ; stage A0(t+2) ; MFMA m4..7 x n-hi
        #pragma unroll
        for (int n = 0; n < NH; ++n) { bh[n][0] = rdB(t, NH + n, 0); bh[n][1] = rdB(t, NH + n, 1); }
        if (t2 < NT) stA(t2, 0);
        cfence(); __builtin_amdgcn_s_barrier();
        __builtin_amdgcn_s_setprio(1);
        #pragma unroll
        for (int m = 0; m < 4; ++m)
            #pragma unroll
            for (int n = 0; n < NH; ++n)
                #pragma unroll
                for (int kk = 0; kk < 2; ++kk)
                    acc[m + 4][NH + n] = __builtin_amdgcn_mfma_f32_16x16x32_bf16(a1[m][kk], bh[n][kk], acc[m + 4][NH + n], 0, 0, 0);
        __builtin_amdgcn_s_setprio(0);
        cfence(); __builtin_amdgcn_s_barrier();
        // ---- phase 3: stage A1(t+2) ; MFMA m0..3 x n-hi ; counted vmcnt
        if (t2 < NT) stA(t2, 1);
        cfence(); __builtin_amdgcn_s_barrier();
        __builtin_amdgcn_s_setprio(1);
        #pragma unroll
        for (int m = 0; m < 4; ++m)
            #pragma unroll
            for (int n = 0; n < NH; ++n)
                #pragma unroll
                for (int kk = 0; kk < 2; ++kk)
                    acc[m][NH + n] = __builtin_amdgcn_mfma_f32_16x16x32_bf16(a0[m][kk], bh[n][kk], acc[m][NH + n], 0, 0, 0);
        __builtin_amdgcn_s_setprio(0);
        if (t2 < NT)      { asm volatile("s_waitcnt vmcnt(4)" ::: "memory"); }
        else if (t1 < NT) { asm volatile("s_waitcnt vmcnt(0)" ::: "memory"); }
        cfence(); __builtin_amdgcn_s_barrier();
    }

    // epilogue: C/D layout col = lane&15, row = (lane>>4)*4 + i
    const size_t crow0 = (size_t)bm * 256 + wr * 128 + (fg << 2);
    const size_t ccol0 = (size_t)bn * BN + wc * WN + frow;
    #pragma unroll
    for (int m = 0; m < 8; ++m)
        #pragma unroll
        for (int n = 0; n < NR; ++n)
            #pragma unroll
            for (int i = 0; i < 4; ++i)
                C[(crow0 + m * 16 + i) * N + ccol0 + n * 16] = (CT)(acc[m][n][i] * scale);
}

// ---------------- row softmax in place over bf16 [rows x 8192] ----------------
__global__ __launch_bounds__(256) void softmax_row(bf16* __restrict__ Z, int cols) {
    __shared__ float buf[8192];   // 32 KB
    __shared__ float red[4];
    const int tid = threadIdx.x;
    bf16* zrow = Z + (size_t)blockIdx.x * cols;

    float lmax = -3.4e38f;
    #pragma unroll
    for (int it = 0; it < 4; ++it) {
        int idx = it * 2048 + tid * 8;
        bf16x8 v = *(const bf16x8*)(zrow + idx);
        #pragma unroll
        for (int j = 0; j < 8; ++j) {
            float f = (float)v[j];
            buf[idx + j] = f;
            lmax = fmaxf(lmax, f);
        }
    }
    #pragma unroll
    for (int o = 32; o; o >>= 1) lmax = fmaxf(lmax, __shfl_xor(lmax, o));
    if ((tid & 63) == 0) red[tid >> 6] = lmax;
    __syncthreads();
    const float gmax = fmaxf(fmaxf(red[0], red[1]), fmaxf(red[2], red[3]));
    __syncthreads();

    float lsum = 0.f;
    #pragma unroll
    for (int it = 0; it < 4; ++it) {
        int idx = it * 2048 + tid * 8;
        #pragma unroll
        for (int j = 0; j < 8; ++j) {
            float e = __expf(buf[idx + j] - gmax);
            buf[idx + j] = e;
            lsum += e;
        }
    }
    #pragma unroll
    for (int o = 32; o; o >>= 1) lsum += __shfl_xor(lsum, o);
    if ((tid & 63) == 0) red[tid >> 6] = lsum;
    __syncthreads();
    const float inv = 1.0f / (red[0] + red[1] + red[2] + red[3]);

    #pragma unroll
    for (int it = 0; it < 4; ++it) {
        int idx = it * 2048 + tid * 8;
        bf16x8 v;
        #pragma unroll
        for (int j = 0; j < 8; ++j) v[j] = (bf16)(buf[idx + j] * inv);
        *(bf16x8*)(zrow + idx) = v;
    }
}

// ---------------- bf16 transpose: VT[c][r] = V[r][c] ----------------
__global__ __launch_bounds__(256) void transpose_bf16(const ushort* __restrict__ V,
                                                      ushort* __restrict__ VT,
                                                      int R, int Ccols) {
    __shared__ ushort tile[32][33];
    const int tx = threadIdx.x, ty = threadIdx.y;
    const int r0 = blockIdx.y * 32, c0 = blockIdx.x * 32;
    #pragma unroll
    for (int i = 0; i < 32; i += 8)
        tile[ty + i][tx] = V[(size_t)(r0 + ty + i) * Ccols + c0 + tx];
    __syncthreads();
    #pragma unroll
    for (int i = 0; i < 32; i += 8)
        VT[(size_t)(c0 + ty + i) * R + r0 + tx] = tile[tx][ty + i];
}

extern "C" void kernel_launch(void* const* d_in, const int* in_sizes, int n_in,
                              void* d_out, int out_size, void* d_ws, size_t ws_size,
                              hipStream_t stream) {
    const float* h  = (const float*)d_in[0];
    const float* wq = (const float*)d_in[1];
    const float* wk = (const float*)d_in[2];
    const float* wv = (const float*)d_in[3];
    float* out = (float*)d_out;

    char* ws = (char*)d_ws;
    bf16* h_bf  = (bf16*)(ws);                          // 16 MB  [8192 x 1024]
    bf16* wq_bf = (bf16*)(ws + (16ull << 20));          //  2 MB
    bf16* wk_bf = (bf16*)(ws + (18ull << 20));          //  2 MB
    bf16* wv_bf = (bf16*)(ws + (20ull << 20));          //  2 MB
    bf16* Q     = (bf16*)(ws + (22ull << 20));          // 16 MB
    bf16* Kb    = (bf16*)(ws + (38ull << 20));          // 16 MB
    bf16* V     = (bf16*)(ws + (54ull << 20));          // 16 MB
    bf16* VT    = (bf16*)(ws + (70ull << 20));          // 16 MB  [1024 x 8192]
    bf16* Z     = (bf16*)(ws + (86ull << 20));          // 128 MB [8192 x 8192]

    // 1) convert inputs to bf16
    cvt_f32_to_bf16<<<8192, 256, 0, stream>>>(h,  h_bf,  (8192 * 1024) / 4);
    cvt_f32_to_bf16<<<1024, 256, 0, stream>>>(wq, wq_bf, (1024 * 1024) / 4);
    cvt_f32_to_bf16<<<1024, 256, 0, stream>>>(wk, wk_bf, (1024 * 1024) / 4);
    cvt_f32_to_bf16<<<1024, 256, 0, stream>>>(wv, wv_bf, (1024 * 1024) / 4);

    // 2) Q = h @ wq^T (scale folded), K = h @ wk^T, V = h @ wv^T   (BN=128 -> 256 blocks)
    const float qscale = 1.0f / 32.0f;   // 1/sqrt(1024)
    gemm8p<bf16, 128><<<256, 512, 0, stream>>>(h_bf, wq_bf, Q,  8192, 1024, 1024, qscale);
    gemm8p<bf16, 128><<<256, 512, 0, stream>>>(h_bf, wk_bf, Kb, 8192, 1024, 1024, 1.0f);
    gemm8p<bf16, 128><<<256, 512, 0, stream>>>(h_bf, wv_bf, V,  8192, 1024, 1024, 1.0f);

    // 3) VT = V^T
    transpose_bf16<<<dim3(1024 / 32, 8192 / 32), dim3(32, 8), 0, stream>>>(
        (const ushort*)V, (ushort*)VT, 8192, 1024);

    // 4) Z = Q @ K^T  (scaled logits, bf16; BN=256 -> 1024 blocks)
    gemm8p<bf16, 256><<<1024, 512, 0, stream>>>(Q, Kb, Z, 8192, 8192, 1024, 1.0f);

    // 5) row softmax in place
    softmax_row<<<8192, 256, 0, stream>>>(Z, 8192);

    // 6) out = beta @ V  ==  beta[8192,8192] @ VT[1024,8192]^T   (BN=128)
    gemm8p<float, 128><<<256, 512, 0, stream>>>(Z, VT, out, 8192, 1024, 8192, 1.0f);
}